// Round 8
// baseline (16.423 us; speedup 1.0000x reference)
//
#include <hip/hip_runtime.h>
#include <math.h>

// out[b,m] = x[b,m] + f(y[b,m]),  y[b,m] = sum_n softmax(A_param)[m,n] * x[b,n]
// f(y) = b2 + sum_h relu(y*W1[h] + b1[h]) * W2[h]  -- piecewise-linear in y,
// approximated by a 512-bin secant table (alpha_k, beta_k) built per block in LDS.
// |y| <= max|x| < 8 since softmaxed A rows make y a convex combination.
//
// R8 vs R7: 2048 blocks x ONE 12KB chunk (was 1024 x two). Halves each block's
// critical path and register-resident data, and (at 4 blocks/CU) splits the grid
// into two scheduling rounds so round-2 reads overlap round-1 writes -- the R7
// structure serialized the whole read stream before the whole write stream.

typedef float f32x2 __attribute__((ext_vector_type(2)));
typedef float f32x4 __attribute__((ext_vector_type(4)));

#define NN 6
#define HH 32
#define NB 512
#define YMIN  (-8.0f)
#define YSPAN (16.0f)
#define INVH  ((float)NB / YSPAN)   // 32.0
#define OFFS  (-YMIN * INVH)        // 256.0
#define BINW  (YSPAN / (float)NB)   // 0.03125
#define F4C   768                   // float4 per chunk (256 pairs * 48B)

__device__ __forceinline__ f32x2 mk2(float a, float b) {
    f32x2 r; r.x = a; r.y = b; return r;
}

__device__ __forceinline__ f32x2 pk_fma(f32x2 a, f32x2 b, f32x2 c) {
#if __has_builtin(__builtin_elementwise_fma)
    return __builtin_elementwise_fma(a, b, c);
#else
    f32x2 r; r.x = fmaf(a.x, b.x, c.x); r.y = fmaf(a.y, b.y, c.y); return r;
#endif
}

// Row-mix + table lookup + residual for one pair (12 floats in v0..v2).
__device__ __forceinline__ void eval_pair(
    f32x4 v0, f32x4 v1, f32x4 v2,
    const float* __restrict__ sA,
    const f32x2* __restrict__ sTab,
    f32x4& o0, f32x4& o1, f32x4& o2)
{
    f32x2 xx[NN];
    xx[0] = mk2(v0.x, v1.z);
    xx[1] = mk2(v0.y, v1.w);
    xx[2] = mk2(v0.z, v2.x);
    xx[3] = mk2(v0.w, v2.y);
    xx[4] = mk2(v1.x, v2.z);
    xx[5] = mk2(v1.y, v2.w);

    f32x2 yy[NN];
#pragma unroll
    for (int m = 0; m < NN; ++m) {
        f32x2 a = mk2(0.f, 0.f);
#pragma unroll
        for (int n = 0; n < NN; ++n) {
            float c = sA[m * NN + n];    // uniform-address LDS broadcast
            a = pk_fma(mk2(c, c), xx[n], a);
        }
        yy[m] = a;
    }

    f32x2 rr[NN];
#pragma unroll
    for (int m = 0; m < NN; ++m) {
#pragma unroll
        for (int half = 0; half < 2; ++half) {
            float yv = half ? yy[m].y : yy[m].x;
            float fi = fmaf(yv, INVH, OFFS);
            fi = fminf(fmaxf(fi, 0.0f), (float)(NB - 1));   // -> v_med3_f32
            int k = (int)fi;
            f32x2 ab = sTab[k];               // ds_read_b64 gather
            float r = fmaf(ab.y, yv, ab.x);
            if (half) rr[m].y = r; else rr[m].x = r;
        }
    }

    o0.x = v0.x + rr[0].x;
    o0.y = v0.y + rr[1].x;
    o0.z = v0.z + rr[2].x;
    o0.w = v0.w + rr[3].x;
    o1.x = v1.x + rr[4].x;
    o1.y = v1.y + rr[5].x;
    o1.z = v1.z + rr[0].y;
    o1.w = v1.w + rr[1].y;
    o2.x = v2.x + rr[2].y;
    o2.y = v2.y + rr[3].y;
    o2.z = v2.z + rr[4].y;
    o2.w = v2.w + rr[5].y;
}

__global__ __launch_bounds__(256, 4) void graph_block_fused(
    const float* __restrict__ x,
    const float* __restrict__ Ap,
    const float* __restrict__ W1p,
    const float* __restrict__ b1p,
    const float* __restrict__ W2p,
    const float* __restrict__ b2p,
    float* __restrict__ out,
    int nF4)
{
    __shared__ float sA[NN * NN];
    __shared__ float sW1[HH], sB1[HH], sW2[HH];
    __shared__ float sB2;
    __shared__ float sEdge[NB + 1];
    __shared__ __align__(16) f32x2 sTab[NB];
    __shared__ __align__(16) float sX[F4C * 4];   // 12KB, one chunk

    const int tid = threadIdx.x;
    const int blockF4 = blockIdx.x * F4C;

    // ---- Issue the chunk's unit-stride float4 loads immediately; the HBM
    //      latency drains under the param/softmax/edge-build work below.
    f32x4 st0, st1, st2;
    {
        int f0 = blockF4 + tid;
        int f1 = blockF4 + 256 + tid;
        int f2 = blockF4 + 512 + tid;
        if (f0 < nF4) st0 = ((const f32x4*)x)[f0];
        if (f1 < nF4) st1 = ((const f32x4*)x)[f1];
        if (f2 < nF4) st2 = ((const f32x4*)x)[f2];
    }

    // ---- Stage params (wave 0) + row-softmax (wave 1).
    if (tid < HH) {
        sW1[tid] = W1p[tid];
        sB1[tid] = b1p[tid];
        sW2[tid] = W2p[tid];
    }
    if (tid == HH) sB2 = b2p[0];
    if (tid >= 64 && tid < 64 + NN) {
        int m = tid - 64;
        float r[NN];
        float mx = -INFINITY;
#pragma unroll
        for (int n = 0; n < NN; ++n) {
            r[n] = Ap[m * NN + n];
            mx = fmaxf(mx, r[n]);
        }
        float s = 0.f;
#pragma unroll
        for (int n = 0; n < NN; ++n) {
            r[n] = expf(r[n] - mx);
            s += r[n];
        }
        float inv = 1.f / s;
#pragma unroll
        for (int n = 0; n < NN; ++n) sA[m * NN + n] = r[n] * inv;
    }
    __syncthreads();   // (1) params + softmax visible

    // ---- f at the 513 bin edges (secant), 2 edges/thread; stage x -> LDS.
    {
        float bb2 = sB2;
        float e0 = YMIN + (float)tid * BINW;
        float e1 = e0 + 256.0f * BINW;
        float f0 = bb2, f1 = bb2;
#pragma unroll
        for (int h = 0; h < HH; ++h) {
            float w1 = sW1[h], bv = sB1[h], w2 = sW2[h];
            f0 = fmaf(fmaxf(fmaf(w1, e0, bv), 0.f), w2, f0);
            f1 = fmaf(fmaxf(fmaf(w1, e1, bv), 0.f), w2, f1);
        }
        sEdge[tid] = f0;
        sEdge[tid + 256] = f1;
        if (tid == 0) {
            float f2 = bb2;
#pragma unroll
            for (int h = 0; h < HH; ++h)
                f2 = fmaf(fmaxf(fmaf(sW1[h], YMIN + YSPAN, sB1[h]), 0.f), sW2[h], f2);
            sEdge[NB] = f2;
        }
    }
    ((f32x4*)sX)[tid]       = st0;   // unit-stride ds_write_b128
    ((f32x4*)sX)[256 + tid] = st1;
    ((f32x4*)sX)[512 + tid] = st2;
    __syncthreads();   // (2) edges + staged x visible

    // ---- Per-bin (alpha, beta) from adjacent edges, 2 bins/thread.
#pragma unroll
    for (int i = 0; i < 2; ++i) {
        int k = tid + i * 256;
        float fa = sEdge[k];
        float fb = sEdge[k + 1];
        float beta = (fb - fa) * INVH;
        float ek = YMIN + (float)k * BINW;
        sTab[k] = mk2(fmaf(-beta, ek, fa), beta);
    }
    __syncthreads();   // (3) table + cross-thread x visible

    // ---- Eval in place in LDS (thread-exclusive 48B slot; 48B lane stride
    //      spreads a wave's 256 words evenly over all 32 banks).
    {
        f32x4* ps = (f32x4*)sX + tid * 3;
        f32x4 v0 = ps[0], v1 = ps[1], v2 = ps[2];
        f32x4 o0, o1, o2;
        eval_pair(v0, v1, v2, sA, sTab, o0, o1, o2);
        ps[0] = o0; ps[1] = o1; ps[2] = o2;
    }
    __syncthreads();   // (4) results visible

    // ---- Unit-stride float4 stores, issued as early as possible.
    {
        int f0 = blockF4 + tid;
        int f1 = blockF4 + 256 + tid;
        int f2 = blockF4 + 512 + tid;
        if (f0 < nF4) ((f32x4*)out)[f0] = ((const f32x4*)sX)[tid];
        if (f1 < nF4) ((f32x4*)out)[f1] = ((const f32x4*)sX)[256 + tid];
        if (f2 < nF4) ((f32x4*)out)[f2] = ((const f32x4*)sX)[512 + tid];
    }
}

extern "C" void kernel_launch(void* const* d_in, const int* in_sizes, int n_in,
                              void* d_out, int out_size, void* d_ws, size_t ws_size,
                              hipStream_t stream) {
    const float* x  = (const float*)d_in[0];
    const float* Ap = (const float*)d_in[1];
    const float* W1 = (const float*)d_in[2];
    const float* b1 = (const float*)d_in[3];
    const float* W2 = (const float*)d_in[4];
    const float* b2 = (const float*)d_in[5];
    float* out = (float*)d_out;

    int nF4 = in_sizes[0] / 4;                    // 1,572,864
    int grid = (nF4 + F4C - 1) / F4C;             // 2048 blocks, one 12KB chunk each
    graph_block_fused<<<grid, 256, 0, stream>>>(x, Ap, W1, b1, W2, b2, out, nF4);
}